// Round 10
// baseline (13027.306 us; speedup 1.0000x reference)
//
#include <hip/hip_runtime.h>
#include <stdint.h>

// ---------------------------------------------------------------------------
// GRUClassifier round 9 = round 8 design + asm fix (v-pointer loads).
// Round-8 compile failure: the "s"(sbase) 64-bit operand of ld_plane8 was
// allocated to a VGPR pair (LLVM uniformity proof broke after restructuring)
// -> invalid saddr. Fix: all asm memory ops use the proven full-VGPR-pointer
// "off" form (compiled+ran in rounds 5-7).
// Design (round 8): consumers load ring data with sc0 only (L2-cached,
// L1-bypass) after an acquire-agent fence (buffer_inv) per step; producers
// publish write-through (sc0 sc1, per-thread drained) + relaxed flags.
// Freshness: back-pressure guarantees all old-version L2 fills happen-before
// producer publishes t; consumer fences after flag-observe, so surviving L2
// lines are version t. 6 GRU stages x 8 e-slices x 2 batch tiles (256 rows)
// + 16 attention blocks (32 rows) = 112 blocks; weights LDS-resident
// (validated round 6); es-major ring [sd*8+es][row][32col] (round 7).
// Numerics (validated round 2): bf16 MFMA inputs, fp32 hidden carry.
// ---------------------------------------------------------------------------

typedef short short8 __attribute__((ext_vector_type(8)));
typedef float floatx4 __attribute__((ext_vector_type(4)));
typedef int intx4 __attribute__((ext_vector_type(4)));
typedef unsigned long long u64;

#define NB 512
#define NT 256
#define NH 256
#define NG 768
#define R_RING 8
#define RSLOT (6 * NB * NH)          // u16 elems per ring slot
#define PLANE 16384                  // u16 elems per [stage,es] plane (32 KB)
#define BTH 512

__device__ __forceinline__ float bf2f(uint16_t v) {
    uint32_t u = ((uint32_t)v) << 16;
    float f;
    __builtin_memcpy(&f, &u, 4);
    return f;
}
__device__ __forceinline__ uint16_t f2bf(float f) {
    uint32_t u;
    __builtin_memcpy(&u, &f, 4);
    uint32_t r = (u + 0x7FFFu + ((u >> 16) & 1u)) >> 16;
    return (uint16_t)r;
}
__device__ __forceinline__ u64 pack4bf(float4 v) {
    u64 a = f2bf(v.x), b = f2bf(v.y), c = f2bf(v.z), d = f2bf(v.w);
    return a | (b << 16) | (c << 32) | (d << 48);
}
__device__ __forceinline__ float sigmoidf_(float x) { return 1.f / (1.f + expf(-x)); }
__device__ __forceinline__ float geluf_(float x) { return 0.5f * x * (1.f + erff(x * 0.70710678118f)); }
__device__ __forceinline__ short8 as_s8(intx4 v) { short8 r; __builtin_memcpy(&r, &v, 16); return r; }

// write-through 16B store + own-thread drain
__device__ __forceinline__ void st_coh16_wait(void* p, intx4 v) {
    asm volatile("global_store_dwordx4 %0, %1, off sc0 sc1\n\ts_waitcnt vmcnt(0)"
                 :: "v"(p), "v"(v) : "memory");
}
// 8 cached (L2-allocate, L1-bypass) loads across the 8 es-planes of a stage
__device__ __forceinline__ void ld_p8(const uint16_t* p, intx4* v) {
    asm volatile(
        "global_load_dwordx4 %0, %8, off sc0\n\t"
        "global_load_dwordx4 %1, %9, off sc0\n\t"
        "global_load_dwordx4 %2, %10, off sc0\n\t"
        "global_load_dwordx4 %3, %11, off sc0\n\t"
        "global_load_dwordx4 %4, %12, off sc0\n\t"
        "global_load_dwordx4 %5, %13, off sc0\n\t"
        "global_load_dwordx4 %6, %14, off sc0\n\t"
        "global_load_dwordx4 %7, %15, off sc0"
        : "=&v"(v[0]), "=&v"(v[1]), "=&v"(v[2]), "=&v"(v[3]),
          "=&v"(v[4]), "=&v"(v[5]), "=&v"(v[6]), "=&v"(v[7])
        : "v"(p), "v"(p + PLANE), "v"(p + 2 * PLANE), "v"(p + 3 * PLANE),
          "v"(p + 4 * PLANE), "v"(p + 5 * PLANE), "v"(p + 6 * PLANE), "v"(p + 7 * PLANE)
        : "memory");
}
__device__ __forceinline__ void wait_vm8(intx4* v) {
    asm volatile("s_waitcnt vmcnt(0)"
                 : "+v"(v[0]), "+v"(v[1]), "+v"(v[2]), "+v"(v[3]),
                   "+v"(v[4]), "+v"(v[5]), "+v"(v[6]), "+v"(v[7])
                 :: "memory");
}
// 6 scattered cached loads (attention staging)
__device__ __forceinline__ void ld_sc6(
    const uint16_t* p0, const uint16_t* p1, const uint16_t* p2,
    const uint16_t* p3, const uint16_t* p4, const uint16_t* p5, intx4* v) {
    asm volatile(
        "global_load_dwordx4 %0, %6, off sc0\n\t"
        "global_load_dwordx4 %1, %7, off sc0\n\t"
        "global_load_dwordx4 %2, %8, off sc0\n\t"
        "global_load_dwordx4 %3, %9, off sc0\n\t"
        "global_load_dwordx4 %4, %10, off sc0\n\t"
        "global_load_dwordx4 %5, %11, off sc0\n\t"
        "s_waitcnt vmcnt(0)"
        : "=&v"(v[0]), "=&v"(v[1]), "=&v"(v[2]), "=&v"(v[3]), "=&v"(v[4]), "=&v"(v[5])
        : "v"(p0), "v"(p1), "v"(p2), "v"(p3), "v"(p4), "v"(p5)
        : "memory");
}

#define PIDX(s, t, bt) ((((s) * NT) + (t)) * 2 + (bt))

// ---------------- small utility kernels ------------------------------------
__global__ void k_cvt(const float* __restrict__ src, uint16_t* __restrict__ dst, int n4) {
    int i = blockIdx.x * blockDim.x + threadIdx.x;
    if (i < n4) {
        float4 v = ((const float4*)src)[i];
        ushort4 o;
        o.x = f2bf(v.x); o.y = f2bf(v.y); o.z = f2bf(v.z); o.w = f2bf(v.w);
        ((ushort4*)dst)[i] = o;
    }
}
__global__ void k_zero(float* __restrict__ p, int n4) {
    int i = blockIdx.x * blockDim.x + threadIdx.x;
    if (i < n4) ((float4*)p)[i] = make_float4(0.f, 0.f, 0.f, 0.f);
}
__global__ void k_sentinel(float* __restrict__ out) {
    int i = blockIdx.x * blockDim.x + threadIdx.x;
    if (i < 1024) out[i] = -99999.0f;
}

// ---------------- encoder: encoded = mish(x @ enc_w^T + enc_b), bf16 out ----
__global__ __launch_bounds__(256) void k_encoder(
    const float* __restrict__ x, const float* __restrict__ enc_w,
    const float* __restrict__ enc_b, uint16_t* __restrict__ enc_out) {
    const int tid = threadIdx.x;
    const int lane = tid & 63, wid = tid >> 6;
    const int q = lane >> 4, l15 = lane & 15;
    const int wm = wid >> 1, wj = wid & 1;
    const int j0 = blockIdx.x * 128, b0 = blockIdx.y * 128;

    __shared__ uint16_t a_s[128 * 72];
    __shared__ uint16_t w_s[128 * 72];

#pragma unroll
    for (int jj = 0; jj < 8; ++jj) {
        int u = tid + jj * 256;
        int r = u >> 4, c4 = (u & 15) * 4;
        float4 va = *(const float4*)&x[(size_t)(b0 + r) * 64 + c4];
        float4 vw = *(const float4*)&enc_w[(size_t)(j0 + r) * 64 + c4];
        *(u64*)&a_s[r * 72 + c4] = pack4bf(va);
        *(u64*)&w_s[r * 72 + c4] = pack4bf(vw);
    }
    __syncthreads();

    floatx4 acc[4][4];
#pragma unroll
    for (int mi = 0; mi < 4; ++mi)
#pragma unroll
        for (int nf = 0; nf < 4; ++nf) acc[mi][nf] = (floatx4){0.f, 0.f, 0.f, 0.f};

#pragma unroll
    for (int kc = 0; kc < 2; ++kc) {
        short8 af[4], bfg[4];
#pragma unroll
        for (int mi = 0; mi < 4; ++mi)
            af[mi] = *(const short8*)&a_s[(wm * 64 + mi * 16 + l15) * 72 + kc * 32 + q * 8];
#pragma unroll
        for (int nf = 0; nf < 4; ++nf)
            bfg[nf] = *(const short8*)&w_s[(wj * 64 + nf * 16 + l15) * 72 + kc * 32 + q * 8];
#pragma unroll
        for (int mi = 0; mi < 4; ++mi)
#pragma unroll
            for (int nf = 0; nf < 4; ++nf)
                acc[mi][nf] = __builtin_amdgcn_mfma_f32_16x16x32_bf16(af[mi], bfg[nf], acc[mi][nf], 0, 0, 0);
    }

#pragma unroll
    for (int nf = 0; nf < 4; ++nf) {
        int j = j0 + wj * 64 + nf * 16 + l15;
        float eb = enc_b[j];
#pragma unroll
        for (int mi = 0; mi < 4; ++mi)
#pragma unroll
            for (int r = 0; r < 4; ++r) {
                int b = b0 + wm * 64 + mi * 16 + q * 4 + r;
                float v = acc[mi][nf][r] + eb;
                float sp = (v > 20.f) ? v : log1pf(expf(v));
                float m = v * tanhf(sp);
                enc_out[(size_t)b * 32768 + j] = f2bf(m);
            }
    }
}

// ---------------- shared memory layouts ------------------------------------
struct SGru {
    uint16_t wgi[96 * 520];   // [3g*32r][K(+8 pad)]
    uint16_t wgh[96 * 264];   // [3g*32r][256+8]
    uint16_t h_out[128 * 32]; // publish staging (half of the 256 rows)
};
struct SAtt {
    uint16_t hbf[6 * 32 * 264];
    float laP[3][3][32];
    float saT[4][32][17];
    float s_s[32], lg_s[32];
};
union SMem { SGru g; SAtt a; };

// ---------------- pipelined scan kernel ------------------------------------
// grid 112 x 512 thr.
//  blk<96: GRU: sd=blk/16, es=(blk%16)>>1, bt=blk&1 (256 rows x 32 e-cols).
//  blk>=96: attention block ab=blk-96 (16 blocks of 32 rows), bt=ab>>3.
// Ring layout: slot[(t&7)] . plane[sd*8+es] (32KB) . row (64B) . col16.
__global__ __launch_bounds__(BTH) void k_scan(
    const uint16_t* __restrict__ enc_bf,
    const uint16_t* __restrict__ wih0_bf, const uint16_t* __restrict__ wihL_bf,
    const uint16_t* __restrict__ whh_bf,
    const float* __restrict__ bih, const float* __restrict__ bhh,
    const uint16_t* __restrict__ law1_bf, const float* __restrict__ la_b1,
    const float* __restrict__ la_w2, const float* __restrict__ la_b2,
    const uint16_t* __restrict__ saw1_bf, const float* __restrict__ sa_b1,
    const float* __restrict__ sa_w2, const float* __restrict__ sa_b2,
    const float* __restrict__ ln_g, const float* __restrict__ ln_b,
    const float* __restrict__ fc_w, const float* __restrict__ fc_b,
    uint16_t* __restrict__ ring, int* produced, int* consumed,
    float* __restrict__ out) {
    const int blk = blockIdx.x;
    const int tid = threadIdx.x;
    const int w = tid >> 6;
    const int lane = tid & 63;
    const int q = lane >> 4, l15 = lane & 15;

    __shared__ SMem sm;

    if (blk < 96) {
        // =================== GRU stage block ===============================
        const int sd = blk >> 4;
        const int l = sd >> 1, dd = sd & 1;
        const int rem = blk & 15;
        const int es = rem >> 1;
        const int bt = rem & 1;
        const int row0 = bt * 256;
        const int Kgi = (l == 0) ? 128 : 512;
        const int ksh = (l == 0) ? 7 : 9;
        const int strgi = Kgi + 8;
        const uint16_t* wih = (l == 0) ? wih0_bf + (size_t)dd * NG * 128
                                       : wihL_bf + (size_t)((l - 1) * 2 + dd) * NG * 512;
        const uint16_t* whhp = whh_bf + (size_t)sd * NG * 256;
        const int ncons = (l < 2) ? 32 : 16;

        // ---- load weights into LDS (once) ----
        for (int flat = tid * 8; flat < 96 * Kgi; flat += BTH * 8) {
            int r = flat >> ksh, c = flat & (Kgi - 1);
            int g = r >> 5, rr = r & 31;
            int srow = g * 256 + es * 32 + rr;
            *(intx4*)&sm.g.wgi[r * strgi + c] = *(const intx4*)&wih[(size_t)srow * Kgi + c];
        }
        for (int flat = tid * 8; flat < 96 * 256; flat += BTH * 8) {
            int r = flat >> 8, c = flat & 255;
            int g = r >> 5, rr = r & 31;
            int srow = g * 256 + es * 32 + rr;
            *(intx4*)&sm.g.wgh[r * 264 + c] = *(const intx4*)&whhp[(size_t)srow * 256 + c];
        }
        float bRs[2], bZs[2], bNs[2], bHNs[2];
        {
            int ba = sd * NG;
#pragma unroll
            for (int sub = 0; sub < 2; ++sub) {
                int e = es * 32 + sub * 16 + l15;
                bRs[sub] = bih[ba + e] + bhh[ba + e];
                bZs[sub] = bih[ba + 256 + e] + bhh[ba + 256 + e];
                bNs[sub] = bih[ba + 512 + e];
                bHNs[sub] = bhh[ba + 512 + e];
            }
        }
        int wofs_gi[2][3], wofs_gh[2][3];
#pragma unroll
        for (int sub = 0; sub < 2; ++sub)
#pragma unroll
            for (int g = 0; g < 3; ++g) {
                wofs_gi[sub][g] = (g * 32 + sub * 16 + l15) * strgi + q * 8;
                wofs_gh[sub][g] = (g * 32 + sub * 16 + l15) * 264 + q * 8;
            }
        float hreg[2][2][4];   // [row-subtile][out-sub][r] fp32 carry
#pragma unroll
        for (int st = 0; st < 2; ++st)
#pragma unroll
            for (int sub = 0; sub < 2; ++sub)
#pragma unroll
                for (int r = 0; r < 4; ++r) hreg[st][sub][r] = 0.f;

        // per-thread in-plane element offsets for the two row-subtiles
        int eoff[2];
#pragma unroll
        for (int st = 0; st < 2; ++st)
            eoff[st] = (row0 + w * 32 + st * 16 + l15) * 32 + q * 8;
        __syncthreads();

        for (int t = 0; t < NT; ++t) {
            // ---- waits (thread 0) ----
            if (tid == 0) {
                if (t >= R_RING) {
                    const int* cp = &consumed[PIDX(sd, t - R_RING, bt)];
                    while (__hip_atomic_load(cp, __ATOMIC_RELAXED, __HIP_MEMORY_SCOPE_AGENT) < ncons)
                        __builtin_amdgcn_s_sleep(1);
                }
                if (t >= 1) {
                    const int* sp = &produced[PIDX(sd, t - 1, bt)];
                    while (__hip_atomic_load(sp, __ATOMIC_RELAXED, __HIP_MEMORY_SCOPE_AGENT) < 8)
                        __builtin_amdgcn_s_sleep(1);
                }
                if (l > 0) {
                    const int* p0 = &produced[PIDX(2 * (l - 1), t, bt)];
                    const int* p1 = &produced[PIDX(2 * (l - 1) + 1, t, bt)];
                    while (__hip_atomic_load(p0, __ATOMIC_RELAXED, __HIP_MEMORY_SCOPE_AGENT) < 8)
                        __builtin_amdgcn_s_sleep(1);
                    while (__hip_atomic_load(p1, __ATOMIC_RELAXED, __HIP_MEMORY_SCOPE_AGENT) < 8)
                        __builtin_amdgcn_s_sleep(1);
                }
            }
            __syncthreads();
            // acquire: invalidate stale local L2/L1 lines
            __builtin_amdgcn_fence(__ATOMIC_ACQUIRE, "agent");

            const uint16_t* gh_base =
                ring + (size_t)((t - 1) & 7) * RSLOT + (size_t)(sd * 8) * PLANE;
            const uint16_t* gi_base =
                ring + (size_t)(t & 7) * RSLOT + (size_t)((l > 0 ? (2 * l - 2) : 0) * 8) * PLANE;

#pragma unroll
            for (int st = 0; st < 2; ++st) {
                // ---- A-fragment loads: av[0..7]=gh(t-1), av[8..23]=gi(t) ----
                intx4 av[24];
                if (t > 0)
                    ld_p8(gh_base + eoff[st], av);
                else {
#pragma unroll
                    for (int i = 0; i < 8; ++i) av[i] = (intx4){0, 0, 0, 0};
                }
                if (l > 0) {
                    ld_p8(gi_base + eoff[st], av + 8);
                    ld_p8(gi_base + 8 * PLANE + eoff[st], av + 16);
                    if (t > 0) wait_vm8(av);
                    wait_vm8(av + 8);
                    wait_vm8(av + 16);
                } else {
                    int rbase = row0 + w * 32 + st * 16 + l15;
                    const uint16_t* eb = enc_bf + ((size_t)rbase << 15) + t * 128 + q * 8;
#pragma unroll
                    for (int kc = 0; kc < 4; ++kc)
                        __builtin_memcpy(&av[8 + kc], eb + kc * 32, 16);
                    if (t > 0) wait_vm8(av);
                }

                // ---- MFMA ----
                floatx4 aR[2], aZ[2], aNi[2], aNh[2];
#pragma unroll
                for (int sub = 0; sub < 2; ++sub) {
                    floatx4 z = (floatx4){0.f, 0.f, 0.f, 0.f};
                    aR[sub] = z; aZ[sub] = z; aNi[sub] = z; aNh[sub] = z;
                }
                const int nkc = Kgi >> 5;
                for (int kc = 0; kc < nkc; ++kc) {
                    short8 afr = as_s8(av[8 + kc]);
#pragma unroll
                    for (int sub = 0; sub < 2; ++sub) {
                        short8 b0f = *(const short8*)&sm.g.wgi[wofs_gi[sub][0] + kc * 32];
                        short8 b1f = *(const short8*)&sm.g.wgi[wofs_gi[sub][1] + kc * 32];
                        short8 b2f = *(const short8*)&sm.g.wgi[wofs_gi[sub][2] + kc * 32];
                        aR[sub]  = __builtin_amdgcn_mfma_f32_16x16x32_bf16(afr, b0f, aR[sub], 0, 0, 0);
                        aZ[sub]  = __builtin_amdgcn_mfma_f32_16x16x32_bf16(afr, b1f, aZ[sub], 0, 0, 0);
                        aNi[sub] = __builtin_amdgcn_mfma_f32_16x16x32_bf16(afr, b2f, aNi[sub], 0, 0, 0);
                    }
                }
#pragma unroll 2
                for (int kc = 0; kc < 8; ++kc) {
                    short8 afr = as_s8(av[kc]);
#pragma unroll
                    for (int sub = 0; sub < 2; ++sub) {
                        short8 b0f = *(const short8*)&sm.g.wgh[wofs_gh[sub][0] + kc * 32];
                        short8 b1f = *(const short8*)&sm.g.wgh[wofs_gh[sub][1] + kc * 32];
                        short8 b2f = *(const short8*)&sm.g.wgh[wofs_gh[sub][2] + kc * 32];
                        aR[sub]  = __builtin_amdgcn_mfma_f32_16x16x32_bf16(afr, b0f, aR[sub], 0, 0, 0);
                        aZ[sub]  = __builtin_amdgcn_mfma_f32_16x16x32_bf16(afr, b1f, aZ[sub], 0, 0, 0);
                        aNh[sub] = __builtin_amdgcn_mfma_f32_16x16x32_bf16(afr, b2f, aNh[sub], 0, 0, 0);
                    }
                }
                // ---- epilogue ----
#pragma unroll
                for (int sub = 0; sub < 2; ++sub) {
#pragma unroll
                    for (int r = 0; r < 4; ++r) {
                        float rr = sigmoidf_(aR[sub][r] + bRs[sub]);
                        float zz = sigmoidf_(aZ[sub][r] + bZs[sub]);
                        float nn = tanhf(aNi[sub][r] + bNs[sub] + rr * (aNh[sub][r] + bHNs[sub]));
                        hreg[st][sub][r] = (1.f - zz) * nn + zz * hreg[st][sub][r];
                    }
                }
            }

            // ---- two-phase publish (h_out holds 128 rows) ----
#pragma unroll
            for (int p = 0; p < 2; ++p) {
                if ((w >> 2) == p) {
#pragma unroll
                    for (int st = 0; st < 2; ++st)
#pragma unroll
                        for (int sub = 0; sub < 2; ++sub)
#pragma unroll
                            for (int r = 0; r < 4; ++r)
                                sm.g.h_out[((w & 3) * 32 + st * 16 + q * 4 + r) * 32 + sub * 16 + l15] =
                                    f2bf(hreg[st][sub][r]);
                }
                __syncthreads();
                {
                    int r = tid >> 2, part = tid & 3;
                    uint16_t* dst = ring + (size_t)(t & 7) * RSLOT
                                  + (size_t)(sd * 8 + es) * PLANE
                                  + (size_t)(row0 + p * 128 + r) * 32 + part * 8;
                    st_coh16_wait(dst, *(const intx4*)&sm.g.h_out[r * 32 + part * 8]);
                }
                __syncthreads();
            }
            if (tid == 0) {
                __hip_atomic_fetch_add(&produced[PIDX(sd, t, bt)], 1,
                                       __ATOMIC_RELAXED, __HIP_MEMORY_SCOPE_AGENT);
                if (l > 0) {
                    __hip_atomic_fetch_add(&consumed[PIDX(2 * l - 2, t, bt)], 1,
                                           __ATOMIC_RELAXED, __HIP_MEMORY_SCOPE_AGENT);
                    __hip_atomic_fetch_add(&consumed[PIDX(2 * l - 1, t, bt)], 1,
                                           __ATOMIC_RELAXED, __HIP_MEMORY_SCOPE_AGENT);
                }
                if (t >= 1)
                    __hip_atomic_fetch_add(&consumed[PIDX(sd, t - 1, bt)], 1,
                                           __ATOMIC_RELAXED, __HIP_MEMORY_SCOPE_AGENT);
            }
        }
        return;
    }

    // =================== attention block (32 rows) =========================
    const int ab = blk - 96;
    const int b0 = ab * 32;
    const int bt = ab >> 3;
    const int lA = w / 3, nfA = w % 3;
    const float b1A = la_b1[lA * 48 + nfA * 16 + l15];
    const float w2A = la_w2[lA * 48 + nfA * 16 + l15];
    float b1B = 0.f, w2B = 0.f;
    if (w == 0) { b1B = la_b1[2 * 48 + 2 * 16 + l15]; w2B = la_w2[2 * 48 + 2 * 16 + l15]; }
    float nacc[32];
#pragma unroll
    for (int j = 0; j < 32; ++j) nacc[j] = 0.f;
    float m_r = -1e30f, d_r = 0.f;
    const int myrow = 4 * w + (lane >> 4);   // softmax row ownership
    const int ci = lane & 15;

    for (int t = 0; t < NT; ++t) {
        if (tid == 0) {
            const int* p4 = &produced[PIDX(4, t, bt)];
            const int* p5 = &produced[PIDX(5, t, bt)];
            while (__hip_atomic_load(p4, __ATOMIC_RELAXED, __HIP_MEMORY_SCOPE_AGENT) < 8)
                __builtin_amdgcn_s_sleep(1);
            while (__hip_atomic_load(p5, __ATOMIC_RELAXED, __HIP_MEMORY_SCOPE_AGENT) < 8)
                __builtin_amdgcn_s_sleep(1);
        }
        __syncthreads();
        __builtin_amdgcn_fence(__ATOMIC_ACQUIRE, "agent");
        // ---- stage all 6 states (32 rows) into hbf ----
        {
            const uint16_t* base = ring + (size_t)(t & 7) * RSLOT;
#pragma unroll
            for (int h = 0; h < 2; ++h) {
                const uint16_t* ps[6];
                int di[6];
#pragma unroll
                for (int i = 0; i < 6; ++i) {
                    int f = (h * 6 + i) * 512 + tid;        // 0..6143
                    int s = f >> 10, c = f & 1023;
                    int r = c >> 5, g = c & 31;
                    int esx = g >> 2, c16 = g & 3;
                    ps[i] = base + (size_t)(s * 8 + esx) * PLANE + (size_t)(b0 + r) * 32 + c16 * 8;
                    di[i] = (s * 32 + r) * 264 + g * 8;
                }
                intx4 v[6];
                ld_sc6(ps[0], ps[1], ps[2], ps[3], ps[4], ps[5], v);
#pragma unroll
                for (int i = 0; i < 6; ++i) *(intx4*)&sm.a.hbf[di[i]] = v[i];
            }
        }
        __syncthreads();
        if (tid == 0) {
#pragma unroll
            for (int s = 0; s < 6; ++s)
                __hip_atomic_fetch_add(&consumed[PIDX(s, t, bt)], 1,
                                       __ATOMIC_RELAXED, __HIP_MEMORY_SCOPE_AGENT);
        }
        // ---- job A: la(lA, nfA) over both row-tiles ----
        {
            floatx4 ac[2];
            ac[0] = (floatx4){0.f, 0.f, 0.f, 0.f};
            ac[1] = (floatx4){0.f, 0.f, 0.f, 0.f};
#pragma unroll 2
            for (int kc = 0; kc < 512; kc += 32) {
                int k = kc + q * 8;
                int s = 2 * lA + (k >= 256 ? 1 : 0);
                short8 bw = *(const short8*)&law1_bf[(size_t)(lA * 48 + nfA * 16 + l15) * 512 + k];
#pragma unroll
                for (int rt = 0; rt < 2; ++rt) {
                    short8 afr = *(const short8*)&sm.a.hbf[(s * 32 + rt * 16 + l15) * 264 + (k & 255)];
                    ac[rt] = __builtin_amdgcn_mfma_f32_16x16x32_bf16(afr, bw, ac[rt], 0, 0, 0);
                }
            }
#pragma unroll
            for (int rt = 0; rt < 2; ++rt)
#pragma unroll
                for (int r = 0; r < 4; ++r) {
                    float v = geluf_(ac[rt][r] + b1A) * w2A;
                    v += __shfl_xor(v, 1, 64);
                    v += __shfl_xor(v, 2, 64);
                    v += __shfl_xor(v, 4, 64);
                    v += __shfl_xor(v, 8, 64);
                    if (l15 == 0) sm.a.laP[lA][nfA][rt * 16 + q * 4 + r] = v;
                }
        }
        // ---- job B ----
        if (w == 0) {           // la(2,2)
            floatx4 ac[2];
            ac[0] = (floatx4){0.f, 0.f, 0.f, 0.f};
            ac[1] = (floatx4){0.f, 0.f, 0.f, 0.f};
#pragma unroll 2
            for (int kc = 0; kc < 512; kc += 32) {
                int k = kc + q * 8;
                int s = 4 + (k >= 256 ? 1 : 0);
                short8 bw = *(const short8*)&law1_bf[(size_t)(2 * 48 + 2 * 16 + l15) * 512 + k];
#pragma unroll
                for (int rt = 0; rt < 2; ++rt) {
                    short8 afr = *(const short8*)&sm.a.hbf[(s * 32 + rt * 16 + l15) * 264 + (k & 255)];
                    ac[rt] = __builtin_amdgcn_mfma_f32_16x16x32_bf16(afr, bw, ac[rt], 0, 0, 0);
                }
            }
#pragma unroll
            for (int rt = 0; rt < 2; ++rt)
#pragma unroll
                for (int r = 0; r < 4; ++r) {
                    float v = geluf_(ac[rt][r] + b1B) * w2B;
                    v += __shfl_xor(v, 1, 64);
                    v += __shfl_xor(v, 2, 64);
                    v += __shfl_xor(v, 4, 64);
                    v += __shfl_xor(v, 8, 64);
                    if (l15 == 0) sm.a.laP[2][2][rt * 16 + q * 4 + r] = v;
                }
        } else if (w <= 4) {    // sa tile nf = w-1 (raw pre-acts)
            int nf = w - 1;
            floatx4 ac[2];
            ac[0] = (floatx4){0.f, 0.f, 0.f, 0.f};
            ac[1] = (floatx4){0.f, 0.f, 0.f, 0.f};
#pragma unroll 2
            for (int kc = 0; kc < 512; kc += 32) {
                int k = kc + q * 8;
                int s = 4 + (k >= 256 ? 1 : 0);
                short8 bw = *(const short8*)&saw1_bf[(size_t)(nf * 16 + l15) * 512 + k];
#pragma unroll
                for (int rt = 0; rt < 2; ++rt) {
                    short8 afr = *(const short8*)&sm.a.hbf[(s * 32 + rt * 16 + l15) * 264 + (k & 255)];
                    ac[rt] = __builtin_amdgcn_mfma_f32_16x16x32_bf16(afr, bw, ac[rt], 0, 0, 0);
                }
            }
#pragma unroll
            for (int rt = 0; rt < 2; ++rt)
#pragma unroll
                for (int r = 0; r < 4; ++r)
                    sm.a.saT[nf][rt * 16 + q * 4 + r][l15] = ac[rt][r];
        }
        __syncthreads();
        // ---- combine (wave 0, two passes of 16 rows) ----
        if (w == 0) {
#pragma unroll
            for (int rp = 0; rp < 2; ++rp) {
                int row = rp * 16 + l15;
                float sv = 0.f;
#pragma unroll
                for (int l = 0; l < 3; ++l)
                    sv += sigmoidf_(sm.a.laP[l][0][row] + sm.a.laP[l][1][row] +
                                    sm.a.laP[l][2][row] + la_b2[l]);
                float a2 = 0.f;
#pragma unroll
                for (int i = 0; i < 16; ++i) {
                    int c = q * 16 + i;
                    float pre = sv * sm.a.saT[q][row][i] + sa_b1[c];
                    a2 += pre * sigmoidf_(pre) * sa_w2[c];
                }
                a2 += __shfl_xor(a2, 16, 64);
                a2 += __shfl_xor(a2, 32, 64);
                if (q == 0 && lane < 16) { sm.a.s_s[row] = sv; sm.a.lg_s[row] = a2 + sa_b2[0]; }
            }
        }
        __syncthreads();
        // ---- online softmax update (wave w owns rows 4w..4w+3) ----
        {
            float lg = sm.a.lg_s[myrow], sv = sm.a.s_s[myrow];
            float mn = fmaxf(m_r, lg);
            float cs = expf(m_r - mn);
            float e = expf(lg - mn);
            m_r = mn;
            d_r = d_r * cs + e;
            float wf = e * sv;
            int st = 4 + (ci >> 3);
            int c0 = (ci & 7) * 32;
            const uint16_t* hp = &sm.a.hbf[(size_t)(st * 32 + myrow) * 264 + c0];
#pragma unroll
            for (int b8 = 0; b8 < 4; ++b8) {
                short8 o = *(const short8*)(hp + b8 * 8);
#pragma unroll
                for (int j = 0; j < 8; ++j)
                    nacc[b8 * 8 + j] = nacc[b8 * 8 + j] * cs + wf * bf2f((uint16_t)o[j]);
            }
        }
        __syncthreads();   // protect hbf/s_s before next step's staging
    }

    // ---- finalize: context -> LN -> FC ----
    {
        float dinv = 1.f / d_r;
        float cv[32];
        float s1 = 0.f, s2 = 0.f;
#pragma unroll
        for (int j = 0; j < 32; ++j) {
            cv[j] = nacc[j] * dinv;
            s1 += cv[j];
            s2 += cv[j] * cv[j];
        }
        s1 += __shfl_xor(s1, 1, 64);  s2 += __shfl_xor(s2, 1, 64);
        s1 += __shfl_xor(s1, 2, 64);  s2 += __shfl_xor(s2, 2, 64);
        s1 += __shfl_xor(s1, 4, 64);  s2 += __shfl_xor(s2, 4, 64);
        s1 += __shfl_xor(s1, 8, 64);  s2 += __shfl_xor(s2, 8, 64);
        float mean = s1 / 512.f;
        float var = s2 / 512.f - mean * mean;
        float rstd = rsqrtf(var + 1e-5f);
        float p0 = 0.f, p1 = 0.f;
#pragma unroll
        for (int j = 0; j < 32; ++j) {
            int g = (ci >> 3) * 256 + (ci & 7) * 32 + j;
            float nv = (cv[j] - mean) * rstd * ln_g[g] + ln_b[g];
            p0 += nv * fc_w[g];
            p1 += nv * fc_w[512 + g];
        }
        p0 += __shfl_xor(p0, 1, 64);  p1 += __shfl_xor(p1, 1, 64);
        p0 += __shfl_xor(p0, 2, 64);  p1 += __shfl_xor(p1, 2, 64);
        p0 += __shfl_xor(p0, 4, 64);  p1 += __shfl_xor(p1, 4, 64);
        p0 += __shfl_xor(p0, 8, 64);  p1 += __shfl_xor(p1, 8, 64);
        if (ci == 0) {
            out[(b0 + myrow) * 2 + 0] = p0 + fc_b[0];
            out[(b0 + myrow) * 2 + 1] = p1 + fc_b[1];
        }
    }
}

// ---------------------------------------------------------------------------
extern "C" void kernel_launch(void* const* d_in, const int* in_sizes, int n_in,
                              void* d_out, int out_size, void* d_ws, size_t ws_size,
                              hipStream_t stream) {
    const float* x     = (const float*)d_in[0];
    const float* enc_w = (const float*)d_in[1];
    const float* enc_b = (const float*)d_in[2];
    const float* wih0  = (const float*)d_in[3];
    const float* wihL  = (const float*)d_in[4];
    const float* whh   = (const float*)d_in[5];
    const float* bih   = (const float*)d_in[6];
    const float* bhh   = (const float*)d_in[7];
    const float* la_w1 = (const float*)d_in[8];
    const float* la_b1 = (const float*)d_in[9];
    const float* la_w2 = (const float*)d_in[10];
    const float* la_b2 = (const float*)d_in[11];
    const float* sa_w1 = (const float*)d_in[12];
    const float* sa_b1 = (const float*)d_in[13];
    const float* sa_w2 = (const float*)d_in[14];
    const float* sa_b2 = (const float*)d_in[15];
    const float* ln_g  = (const float*)d_in[16];
    const float* ln_b  = (const float*)d_in[17];
    const float* fc_w  = (const float*)d_in[18];
    const float* fc_b  = (const float*)d_in[19];
    float* out = (float*)d_out;

    uint8_t* wsb = (uint8_t*)d_ws;
    size_t off = 0;
    auto alloc = [&](size_t bytes) -> void* {
        void* p = wsb + off;
        off += (bytes + 255) & ~(size_t)255;
        return p;
    };
    uint16_t* enc_bf  = (uint16_t*)alloc((size_t)NB * 32768 * 2);          // 33.55 MB
    uint16_t* wih0_bf = (uint16_t*)alloc((size_t)2 * NG * 128 * 2);        // 0.39 MB
    uint16_t* wihL_bf = (uint16_t*)alloc((size_t)2 * 2 * NG * 512 * 2);    // 3.15 MB
    uint16_t* whh_bf  = (uint16_t*)alloc((size_t)3 * 2 * NG * 256 * 2);    // 2.36 MB
    uint16_t* law1_bf = (uint16_t*)alloc((size_t)3 * 48 * 512 * 2);        // 0.15 MB
    uint16_t* saw1_bf = (uint16_t*)alloc((size_t)64 * 512 * 2);            // 0.07 MB
    uint16_t* ring    = (uint16_t*)alloc((size_t)R_RING * RSLOT * 2);      // 12.58 MB
    int*      produced= (int*)alloc((size_t)6 * NT * 2 * 4);               // 12 KB
    int*      consumed= (int*)alloc((size_t)6 * NT * 2 * 4);               // 12 KB
    // total ~52.3 MB

    if (ws_size < off) {
        k_sentinel<<<4, 256, 0, stream>>>(out);
        return;
    }

    auto cvt = [&](const float* s, uint16_t* dmem, int n) {
        int n4 = n / 4;
        k_cvt<<<(n4 + 255) / 256, 256, 0, stream>>>(s, dmem, n4);
    };
    cvt(wih0, wih0_bf, 196608);
    cvt(wihL, wihL_bf, 1572864);
    cvt(whh, whh_bf, 1179648);
    cvt(la_w1, law1_bf, 73728);
    cvt(sa_w1, saw1_bf, 32768);
    // zero produced+consumed (contiguous: 6144 ints = 1536 float4)
    k_zero<<<6, 256, 0, stream>>>((float*)produced, 1536);

    k_encoder<<<dim3(256, 4), 256, 0, stream>>>(x, enc_w, enc_b, enc_bf);

    k_scan<<<112, BTH, 0, stream>>>(enc_bf, wih0_bf, wihL_bf, whh_bf,
                                    bih, bhh, law1_bf, la_b1, la_w2, la_b2,
                                    saw1_bf, sa_b1, sa_w2, sa_b2,
                                    ln_g, ln_b, fc_w, fc_b,
                                    ring, produced, consumed, out);
}